// Round 7
// baseline (52.255 us; speedup 1.0000x reference)
//
#include <hip/hip_runtime.h>
#include <hip/hip_bf16.h>

typedef unsigned int   u32;
typedef unsigned short u16;

#define NN   8192
#define DD   128
#define CCH  32            // column chunks
#define CHUNK (NN / CCH)   // 256 columns per block (== blockDim)
#define NTJ  (CHUNK / 32)  // 8 j-tiles of 32 rows
#define NIB  (NN / 256)    // 32 i-blocks

#define LOG2E 1.4426950408889634f
#define LN2F  0.6931471805599453f
#define BIAS  32.0f

typedef __bf16 bf16x8 __attribute__((ext_vector_type(8)));
typedef float  f32x16 __attribute__((ext_vector_type(16)));
typedef float  f32x2  __attribute__((ext_vector_type(2)));

__device__ __forceinline__ u16 f2bf(float x) {
    u32 u = __float_as_uint(x);
    u += 0x7fffu + ((u >> 16) & 1u);   // round-to-nearest-even
    return (u16)(u >> 16);
}

// One wave per row: convert z1,z2 to bf16, compute -sq2*log2e - BIAS and fp32 diagonal.
__global__ __launch_bounds__(256) void prep_kernel(
    const float* __restrict__ z1, const float* __restrict__ z2,
    u32* __restrict__ b1, u32* __restrict__ b2,
    float* __restrict__ negsq2b, float* __restrict__ diag)
{
    int row  = blockIdx.x * 4 + (threadIdx.x >> 6);
    int lane = threadIdx.x & 63;
    float2 a = reinterpret_cast<const float2*>(z1)[row * 64 + lane];
    float2 b = reinterpret_cast<const float2*>(z2)[row * 64 + lane];
    b1[row * 64 + lane] = (u32)f2bf(a.x) | ((u32)f2bf(a.y) << 16);
    b2[row * 64 + lane] = (u32)f2bf(b.x) | ((u32)f2bf(b.y) << 16);
    float dot = a.x * b.x + a.y * b.y;
    float sq  = b.x * b.x + b.y * b.y;
    #pragma unroll
    for (int o = 32; o > 0; o >>= 1) {
        dot += __shfl_xor(dot, o);
        sq  += __shfl_xor(sq, o);
    }
    if (lane == 0) {
        negsq2b[row] = -sq * LOG2E - BIAS;
        diag[row]    = 2.0f * dot - sq;
    }
}

// R7: barrier-free streaming design. Each wave owns 64 i-cols (z1 frags in regs)
// and sweeps 8 j-tiles of 32 rows, loading A-fragments of z2 DIRECTLY from global:
//   av[kk] = b2[(j0 + t*32 + (lane&31))*DD + kk*16 + (lane>>5)*8]  (16B, bf16x8)
// Within a block all 4 waves read the same 8KB/tile (L1-shared); the XCD swizzle
// keeps the full 2MB b2 in each XCD's private L2. No LDS tile, no per-tile
// __syncthreads, no global_load_lds -> waves are independent latency-hiding
// streams. (R6 post-mortem: staging+barriers at 2 blocks/CU serialized the
// whole kernel; b2 is cache-resident so staging bought nothing.)
// mfma_f32_32x32x16_bf16, swapped operands: D[j][i] = z2_j . z1_i.
__global__ __launch_bounds__(256) void score_kernel(
    const u16* __restrict__ b1, const u16* __restrict__ b2,
    const float* __restrict__ negsq2b, float* __restrict__ partS)
{
    __shared__ alignas(16) float nqs[CHUNK];       // 1 KB
    const int tid  = threadIdx.x;
    const int lane = tid & 63;
    const int wid  = tid >> 6;
    const int r    = lane & 31, hi = lane >> 5;

    const int f     = blockIdx.x;
    const int chunk = (f >> 3) & 31;               // 32 chunks per XCD
    const int iblk  = (f & 7) * 4 + (f >> 8);      // 4 i-blocks per XCD (bijective)
    const int j0    = chunk * CHUNK;
    const int i0w   = iblk * 256 + wid * 64;

    // z1 fragments (B operand), register-resident: 2 spans x 8 k-slices
    bf16x8 zf0[8], zf1[8];
    #pragma unroll
    for (int kk = 0; kk < 8; ++kk) {
        zf0[kk] = *reinterpret_cast<const bf16x8*>(b1 + (size_t)(i0w + r)      * DD + kk * 16 + hi * 8);
        zf1[kk] = *reinterpret_cast<const bf16x8*>(b1 + (size_t)(i0w + 32 + r) * DD + kk * 16 + hi * 8);
    }
    nqs[tid] = negsq2b[j0 + tid];                  // CHUNK == blockDim == 256
    __syncthreads();                               // once; nqs visible to all waves

    f32x2 sA0 = {0.f, 0.f}, sA1 = {0.f, 0.f}, sB0 = {0.f, 0.f}, sB1 = {0.f, 0.f};
    const f32x2 c2 = {2.0f * LOG2E, 2.0f * LOG2E};

    #pragma unroll 2
    for (int t = 0; t < NTJ; ++t) {
        // A-fragments straight from global (L1/L2-resident)
        const u16* bp = b2 + (size_t)(j0 + t * 32 + r) * DD + hi * 8;
        bf16x8 av[8];
        #pragma unroll
        for (int kk = 0; kk < 8; ++kk)
            av[kk] = *reinterpret_cast<const bf16x8*>(bp + kk * 16);

        f32x16 acc0 = {0.f}; f32x16 acc1 = {0.f};
        #pragma unroll
        for (int kk = 0; kk < 8; ++kk) {
            acc0 = __builtin_amdgcn_mfma_f32_32x32x16_bf16(av[kk], zf0[kk], acc0, 0, 0, 0);
            acc1 = __builtin_amdgcn_mfma_f32_32x32x16_bf16(av[kk], zf1[kk], acc1, 0, 0, 0);
        }

        const float* nqb = &nqs[t * 32 + 4 * hi];
        float4 nq0 = *reinterpret_cast<const float4*>(nqb);
        float4 nq1 = *reinterpret_cast<const float4*>(nqb + 8);
        float4 nq2 = *reinterpret_cast<const float4*>(nqb + 16);
        float4 nq3 = *reinterpret_cast<const float4*>(nqb + 24);
        const float4 nqm[4] = {nq0, nq1, nq2, nq3};
        #pragma unroll
        for (int m = 0; m < 4; ++m) {
            f32x2 n01 = {nqm[m].x, nqm[m].y}, n23 = {nqm[m].z, nqm[m].w};
            f32x2 a01 = {acc0[4*m],   acc0[4*m+1]}, a23 = {acc0[4*m+2], acc0[4*m+3]};
            f32x2 t01 = a01 * c2 + n01, t23 = a23 * c2 + n23;
            f32x2 e01 = {__builtin_amdgcn_exp2f(t01.x), __builtin_amdgcn_exp2f(t01.y)};
            f32x2 e23 = {__builtin_amdgcn_exp2f(t23.x), __builtin_amdgcn_exp2f(t23.y)};
            sA0 += e01; sA1 += e23;
            f32x2 b01 = {acc1[4*m],   acc1[4*m+1]}, b23 = {acc1[4*m+2], acc1[4*m+3]};
            f32x2 u01 = b01 * c2 + n01, u23 = b23 * c2 + n23;
            f32x2 f01 = {__builtin_amdgcn_exp2f(u01.x), __builtin_amdgcn_exp2f(u01.y)};
            f32x2 f23 = {__builtin_amdgcn_exp2f(u23.x), __builtin_amdgcn_exp2f(u23.y)};
            sB0 += f01; sB1 += f23;
        }
    }

    float sum0 = (sA0.x + sA0.y) + (sA1.x + sA1.y);
    float sum1 = (sB0.x + sB0.y) + (sB1.x + sB1.y);
    sum0 += __shfl_xor(sum0, 32);          // combine hi=0/1 j-halves per i
    sum1 += __shfl_xor(sum1, 32);
    if (hi == 0) {
        partS[(size_t)chunk * NN + i0w + r]      = sum0;
        partS[(size_t)chunk * NN + i0w + 32 + r] = sum1;
    }
}

// Combine the 32 column-chunk partials per row, form lse - diag, block-reduce.
__global__ __launch_bounds__(256) void finalize1_kernel(
    const float* __restrict__ partS, const float* __restrict__ diag,
    float* __restrict__ blocksum)
{
    __shared__ float red[4];
    int r = blockIdx.x * 256 + threadIdx.x;
    float s = 0.f;
    #pragma unroll
    for (int c = 0; c < CCH; ++c) s += partS[(size_t)c * NN + r];
    float lse = (BIAS + __builtin_amdgcn_logf(s)) * LN2F;   // v_log_f32 = log2
    float acc = lse - diag[r];
    #pragma unroll
    for (int o = 32; o > 0; o >>= 1) acc += __shfl_xor(acc, o);
    int lane = threadIdx.x & 63, wid = threadIdx.x >> 6;
    if (lane == 0) red[wid] = acc;
    __syncthreads();
    if (threadIdx.x == 0)
        blocksum[blockIdx.x] = red[0] + red[1] + red[2] + red[3];
}

__global__ void finalize2_kernel(const float* __restrict__ blocksum, float* __restrict__ out)
{
    int lane = threadIdx.x;
    float v = (lane < 32) ? blocksum[lane] : 0.f;
    #pragma unroll
    for (int o = 32; o > 0; o >>= 1) v += __shfl_xor(v, o);
    if (lane == 0) out[0] = v * (1.0f / (float)NN);
}

extern "C" void kernel_launch(void* const* d_in, const int* in_sizes, int n_in,
                              void* d_out, int out_size, void* d_ws, size_t ws_size,
                              hipStream_t stream)
{
    const float* z1 = (const float*)d_in[0];
    const float* z2 = (const float*)d_in[1];
    char* ws = (char*)d_ws;

    const size_t bf_bytes = (size_t)NN * DD * 2;   // 2 MB each
    u32*   b1       = (u32*)ws;
    u32*   b2       = (u32*)(ws + bf_bytes);
    float* negsq2b  = (float*)(ws + 2 * bf_bytes);
    float* diag     = (float*)(ws + 2 * bf_bytes + (size_t)NN * 4);
    float* partS    = (float*)(ws + 2 * bf_bytes + (size_t)NN * 8);
    float* blocksum = (float*)(ws + 2 * bf_bytes + (size_t)NN * 8 + (size_t)CCH * NN * 4);
    float* out      = (float*)d_out;

    prep_kernel<<<NN / 4, 256, 0, stream>>>(z1, z2, b1, b2, negsq2b, diag);
    score_kernel<<<CCH * NIB, 256, 0, stream>>>((const u16*)b1, (const u16*)b2, negsq2b, partS);
    finalize1_kernel<<<NN / 256, 256, 0, stream>>>(partS, diag, blocksum);
    finalize2_kernel<<<1, 64, 0, stream>>>(blocksum, out);
}